// Round 4
// baseline (331.983 us; speedup 1.0000x reference)
//
#include <hip/hip_runtime.h>
#include <math.h>
#include <stdint.h>

// ScaleAdaptiveRouter on MI355X (gfx950) — Round 4
// T=16384, H=2048, E=64, K=2112, top-2.
//
// R3 was LDS-issue-bound: wave-uniform b128 broadcasts (16 B useful / slot),
// 32768 reads/CU ~= 164 us ~= measured 170 us. R4 transposes the mapping:
//   lane = token (64 tok/block), wave = 8-expert slice (8 waves, 512 thr).
//   x-tile staged via VGPRs with XOR swizzle (chunk c of token t at c^(t&15))
//     -> per-lane ds_read_b128 at the 8-dword/bank BW floor, 64x fewer reads.
//   W repacked [k4][e] (prep kernel) -> lane-invariant 128 B loads -> s_load
//     (scalar pipe), zero VALU/LDS cost.
//   Top-2: per-lane scan of 8 logits, cross-wave merge via LDS candidates
//     (exact lowest-index tie-break), coalesced composed store.

#define H_DIM 2048
#define K_TOTAL 2112
#define E_DIM 64
#define SE_DIM 64
#define BK 64
#define NKB (H_DIM / BK)        // 32
#define TPB 64                  // tokens per block
#define NBLOCKS (16384 / TPB)   // 256
#define NK4 (K_TOTAL / 4)       // 528
#define EPW 8                   // experts per wave

// ---- prep: W2[k4*64 + e] = float4(W[e][4k4 .. 4k4+3]) ----
__global__ void pack_w_kernel(const float* __restrict__ W, float4* __restrict__ W2) {
    int tid = blockIdx.x * 256 + threadIdx.x;      // 0 .. 33791
    int e  = tid / NK4;
    int k4 = tid - e * NK4;
    float4 v = *(const float4*)(W + (size_t)e * K_TOTAL + 4 * k4);
    W2[(size_t)k4 * E_DIM + e] = v;
}

__launch_bounds__(512)
__global__ void ScaleAdaptiveRouter_kernel(const float* __restrict__ x,
                                           const float* __restrict__ se,
                                           const float4* __restrict__ W2,
                                           const float* __restrict__ noise,
                                           const int* __restrict__ sidx,
                                           float* __restrict__ out) {
    __shared__ __align__(16) float xs[2][TPB * BK];   // 2 x 16 KB x-tiles
    __shared__ float4 cand[8 * TPB];                  // 8 KB top-2 candidates
    __shared__ float4 res[TPB];                       // 1 KB merged results

    const int tid  = threadIdx.x;
    const int lane = tid & 63;                                  // token within block
    const int wave = __builtin_amdgcn_readfirstlane((int)(tid >> 6));
    const int e0   = wave * EPW;                                // this wave's experts
    const int swz  = lane & 15;
    const int tok0 = blockIdx.x * TPB;

    // staging decomposition: thread -> (token t0 / t0+32, f4-chunk c0)
    const int t0 = tid >> 4;            // 0..31
    const int c0 = tid & 15;
    const int soff0 = t0 * BK + ((c0 ^ (t0 & 15)) << 2);        // swizzled LDS float-offset
    const int soff1 = soff0 + 32 * BK;                          // (t0+32)&15 == t0&15

    const float* xg = x + (size_t)tok0 * H_DIM;

    // issue tile 0 global loads
    float4 ra0 = *(const float4*)(xg + (size_t)t0 * H_DIM + c0 * 4);
    float4 ra1 = *(const float4*)(xg + (size_t)(t0 + 32) * H_DIM + c0 * 4);

    // tail: emb . W[e, 2048:2112] for this wave's 8 experts (uniform operands)
    const float* emb = se + (*sidx) * SE_DIM;
    float acc[EPW];
    #pragma unroll
    for (int i = 0; i < EPW; ++i) acc[i] = 0.0f;
    #pragma unroll
    for (int j4 = 0; j4 < SE_DIM / 4; ++j4) {
        float4 e4 = *(const float4*)(emb + 4 * j4);
        #pragma unroll
        for (int i = 0; i < EPW; ++i) {
            float4 wv = W2[(size_t)(512 + j4) * E_DIM + e0 + i];   // uniform -> s_load
            acc[i] = fmaf(e4.x, wv.x, acc[i]);
            acc[i] = fmaf(e4.y, wv.y, acc[i]);
            acc[i] = fmaf(e4.z, wv.z, acc[i]);
            acc[i] = fmaf(e4.w, wv.w, acc[i]);
        }
    }

    // store tile 0 (swizzled), issue tile 1 loads
    *(float4*)&xs[0][soff0] = ra0;
    *(float4*)&xs[0][soff1] = ra1;
    float4 rb0 = *(const float4*)(xg + (size_t)t0 * H_DIM + BK + c0 * 4);
    float4 rb1 = *(const float4*)(xg + (size_t)(t0 + 32) * H_DIM + BK + c0 * 4);
    float4 nr0, nr1;

    // ---- K loop: 1 barrier/tile; store kb+1, issue kb+2, compute kb ----
    for (int kb = 0; kb < NKB; ++kb) {
        __syncthreads();                       // publish tile kb stores
        if (kb + 1 < NKB) {                    // tile kb+1 into other buffer
            *(float4*)&xs[(kb + 1) & 1][soff0] = rb0;   // waits vmcnt on rb
            *(float4*)&xs[(kb + 1) & 1][soff1] = rb1;
        }
        if (kb + 2 < NKB) {                    // issue tile kb+2 loads
            rb0 = *(const float4*)(xg + (size_t)t0 * H_DIM + (kb + 2) * BK + c0 * 4);
            rb1 = *(const float4*)(xg + (size_t)(t0 + 32) * H_DIM + (kb + 2) * BK + c0 * 4);
        } else if (kb == NKB - 2) {            // dead slot: prefetch noise tile
            nr0 = *(const float4*)(noise + (size_t)(tok0 + t0) * E_DIM + c0 * 4);
            nr1 = *(const float4*)(noise + (size_t)(tok0 + t0 + 32) * E_DIM + c0 * 4);
        }

        const float*  xb = xs[kb & 1];
        const float4* wk = W2 + (size_t)(kb * 16) * E_DIM + e0;   // uniform base
        #pragma unroll
        for (int j = 0; j < 16; ++j) {
            // per-lane full-width read, swizzle -> 8 dwords/bank (BW floor)
            float4 xv = *(const float4*)&xb[lane * BK + ((j ^ swz) << 2)];
            #pragma unroll
            for (int i = 0; i < EPW; ++i) {
                float4 wv = wk[(size_t)j * E_DIM + i];            // uniform -> s_load
                acc[i] = fmaf(xv.x, wv.x, acc[i]);
                acc[i] = fmaf(xv.y, wv.y, acc[i]);
                acc[i] = fmaf(xv.z, wv.z, acc[i]);
                acc[i] = fmaf(xv.w, wv.w, acc[i]);
            }
        }
    }

    // ---- noise through the same swizzled LDS path (xs[0] readers all done) ----
    *(float4*)&xs[0][soff0] = nr0;
    *(float4*)&xs[0][soff1] = nr1;
    __syncthreads();

    float4 n0 = *(const float4*)&xs[0][lane * BK + (((2 * wave)     ^ swz) << 2)];
    float4 n1 = *(const float4*)&xs[0][lane * BK + (((2 * wave + 1) ^ swz) << 2)];

    float lg[EPW];
    lg[0] = fmaf(n0.x, 0.1f, acc[0]);
    lg[1] = fmaf(n0.y, 0.1f, acc[1]);
    lg[2] = fmaf(n0.z, 0.1f, acc[2]);
    lg[3] = fmaf(n0.w, 0.1f, acc[3]);
    lg[4] = fmaf(n1.x, 0.1f, acc[4]);
    lg[5] = fmaf(n1.y, 0.1f, acc[5]);
    lg[6] = fmaf(n1.z, 0.1f, acc[6]);
    lg[7] = fmaf(n1.w, 0.1f, acc[7]);

    // per-lane top-2 of this wave's 8 experts (strict > keeps lowest index)
    float v1 = lg[0]; int i1 = 0;
    float v2 = -__builtin_inff(); int i2 = 0;
    #pragma unroll
    for (int i = 1; i < EPW; ++i) {
        if (lg[i] > v1)      { v2 = v1; i2 = i1; v1 = lg[i]; i1 = i; }
        else if (lg[i] > v2) { v2 = lg[i]; i2 = i; }
    }
    cand[wave * TPB + lane] = make_float4(v1, __int_as_float(e0 + i1),
                                          v2, __int_as_float(e0 + i2));
    __syncthreads();

    // ---- wave 0: merge 8 candidate pairs per token (ascending w => ties -> lowest idx) ----
    if (wave == 0) {
        float4 c = cand[lane];
        float V1 = c.x, V2 = c.z;
        int   I1 = __float_as_int(c.y), I2 = __float_as_int(c.w);
        #pragma unroll
        for (int w = 1; w < 8; ++w) {
            c = cand[w * TPB + lane];
            if (c.x > V1) {
                if (c.z > V1) { V2 = c.z; I2 = __float_as_int(c.w); }
                else          { V2 = V1;  I2 = I1; }
                V1 = c.x; I1 = __float_as_int(c.y);
            } else if (c.x > V2) {
                V2 = c.x; I2 = __float_as_int(c.y);
            }
        }
        // softmax denom cancels in top-2 renorm
        float d   = expf(V2 - V1);               // <= 1
        float inv = 1.0f / (1.0f + d);
        res[lane] = make_float4(inv, __int_as_float(I1), d * inv, __int_as_float(I2));
    }
    __syncthreads();

    // ---- coalesced composed store: block's 64x64 output rows ----
    float4* outb = (float4*)out + (size_t)blockIdx.x * (TPB * E_DIM / 4);
    #pragma unroll
    for (int pp = 0; pp < 2; ++pp) {
        int p = tid + pp * 512;                  // f4 index in block region
        int t = p >> 4, cc = p & 15;
        float4 r = res[t];                       // broadcast-ish LDS read
        int ri1 = __float_as_int(r.y), ri2 = __float_as_int(r.w);
        int e = cc * 4;
        float4 o;
        o.x = (e + 0 == ri1) ? r.x : (e + 0 == ri2) ? r.z : 0.0f;
        o.y = (e + 1 == ri1) ? r.x : (e + 1 == ri2) ? r.z : 0.0f;
        o.z = (e + 2 == ri1) ? r.x : (e + 2 == ri2) ? r.z : 0.0f;
        o.w = (e + 3 == ri1) ? r.x : (e + 3 == ri2) ? r.z : 0.0f;
        outb[p] = o;
    }
}

extern "C" void kernel_launch(void* const* d_in, const int* in_sizes, int n_in,
                              void* d_out, int out_size, void* d_ws, size_t ws_size,
                              hipStream_t stream) {
    const float* x     = (const float*)d_in[0];
    const float* se    = (const float*)d_in[1];
    const float* W     = (const float*)d_in[2];
    const float* noise = (const float*)d_in[3];
    const int*   sidx  = (const int*)d_in[4];
    float* out = (float*)d_out;
    float4* W2 = (float4*)d_ws;      // 528 * 64 * 16 B = 540672 B

    hipLaunchKernelGGL(pack_w_kernel, dim3((E_DIM * NK4) / 256), dim3(256), 0, stream, W, W2);
    hipLaunchKernelGGL(ScaleAdaptiveRouter_kernel, dim3(NBLOCKS), dim3(512), 0, stream,
                       x, se, W2, noise, sidx, out);
}